// Round 1
// baseline (11220.045 us; speedup 1.0000x reference)
//
#include <hip/hip_runtime.h>
#include <math.h>

// Problem constants
// B=16, S=128, H=512, V=50000, N=5, R=2, Wd=512, XI=2573
#define EPSC 1e-6f

// xi split offsets: rk:0 rb:1024 wk:1026 wb:1538 e:1539 v:2051 fg:2563 ga:2565 gw:2566 pi:2567
// ws layout (float offsets)
#define OFF_H   0u          // hbuf[2][16][512]
#define OFF_C   16384u      // c[16][512]
#define OFF_R   24576u      // r[16][1024]
#define OFF_M   40960u      // M[16][5][512]
#define OFF_U   81920u      // u[16][5]
#define OFF_P   82000u      // p[16][5]
#define OFF_L   82080u      // L[16][25]
#define OFF_WR  82480u      // wr[16][10]
#define OFF_WW  82640u      // ww[16][5]
#define STATE_END 82720u
#define OFF_XI  82720u      // xi[16][2573]
#define OFF_GX  123888u     // gates_x[128][16][2048]
#define OFF_HR  4318192u    // hr[128][16][1536]
// total 7463920 floats = 29.86 MB

__device__ __forceinline__ float sigmf(float x) { return 1.0f / (1.0f + expf(-x)); }
__device__ __forceinline__ float oneplusf(float x) {
    // 1 + softplus(x), numerically stable
    return 1.0f + fmaxf(x, 0.0f) + log1pf(expf(-fabsf(x)));
}

// ---------------------------------------------------------------------------
// Prologue: gates_x[tok][col] = b_lstm[col] + sum_{k<512} emb[src_tok,k]*W_ih[col,k]
// tok = s*16+b (2048 tokens), col in [0,2048). GEMM M=2048,N=2048,K=512.
// ---------------------------------------------------------------------------
__global__ __launch_bounds__(256) void k_embgx(
    const int* __restrict__ src, const float* __restrict__ emb,
    const float* __restrict__ W_ih, const float* __restrict__ b_lstm,
    float* __restrict__ gx)
{
    __shared__ float As[16][65];
    __shared__ float Bs[16][65];
    const int tid = threadIdx.x;
    const int bm = blockIdx.x, bn = blockIdx.y;
    const int tm = tid >> 4, tn = tid & 15;
    float acc[4][4] = {};
    for (int k0 = 0; k0 < 512; k0 += 16) {
#pragma unroll
        for (int i = 0; i < 4; i++) {
            int idx = tid + 256 * i;
            int m = idx >> 4, kk = idx & 15;
            int tok = bm * 64 + m;
            int row = src[(tok & 15) * 128 + (tok >> 4)];   // src[b*128+s]
            As[kk][m] = emb[(size_t)row * 512 + k0 + kk];
        }
#pragma unroll
        for (int i = 0; i < 4; i++) {
            int idx = tid + 256 * i;
            int n = idx >> 4, kk = idx & 15;
            Bs[kk][n] = W_ih[(size_t)(bn * 64 + n) * 1536 + k0 + kk];
        }
        __syncthreads();
#pragma unroll
        for (int kk = 0; kk < 16; kk++) {
            float a[4], bv[4];
#pragma unroll
            for (int i = 0; i < 4; i++) a[i] = As[kk][tm * 4 + i];
#pragma unroll
            for (int j = 0; j < 4; j++) bv[j] = Bs[kk][tn * 4 + j];
#pragma unroll
            for (int i = 0; i < 4; i++)
#pragma unroll
                for (int j = 0; j < 4; j++) acc[i][j] += a[i] * bv[j];
        }
        __syncthreads();
    }
#pragma unroll
    for (int i = 0; i < 4; i++) {
        int tok = bm * 64 + tm * 4 + i;
#pragma unroll
        for (int j = 0; j < 4; j++) {
            int col = bn * 64 + tn * 4 + j;
            gx[(size_t)tok * 2048 + col] = acc[i][j] + b_lstm[col];
        }
    }
}

// ---------------------------------------------------------------------------
// Per-step: recurrent gates + fused LSTM update.
// gates[b,col] = gates_x[t,b,col] + sum_{k<512} W_hh[col,k]*h[b,k]
//                                 + sum_{512<=k<1536} W_ih[col,k]*r[b,k-512]
// Block: 2 j values (8 gate-columns), all 16 batches. Grid 256.
// ---------------------------------------------------------------------------
__global__ __launch_bounds__(256) void k_lstm(int t,
    const float* __restrict__ W_ih, const float* __restrict__ W_hh,
    const float* __restrict__ gx, const float* __restrict__ h_in,
    const float* __restrict__ r_in, float* __restrict__ h_out,
    float* __restrict__ cbuf, float* __restrict__ hr)
{
    __shared__ float xin_s[16][132];
    __shared__ float ws_s[8][132];
    __shared__ float part[2][8][16];
    const int tid = threadIdx.x;
    const int j0 = blockIdx.x * 2;
    const int ks = tid >> 7;         // k-split 0/1
    const int cl = (tid >> 4) & 7;   // local col 0..7
    const int bb = tid & 15;         // batch
    float acc = 0.f;
    for (int k0 = 0; k0 < 1536; k0 += 128) {
#pragma unroll
        for (int i = 0; i < 8; i++) {
            int idx = tid + 256 * i;          // 16*128 = 2048
            int b_ = idx >> 7, kk = idx & 127;
            int k = k0 + kk;
            xin_s[b_][kk] = (k < 512) ? h_in[b_ * 512 + k] : r_in[b_ * 1024 + (k - 512)];
        }
#pragma unroll
        for (int i = 0; i < 4; i++) {
            int idx = tid + 256 * i;          // 8*128 = 1024
            int c_ = idx >> 7, kk = idx & 127;
            int k = k0 + kk;
            int cg = (c_ >> 1) * 512 + j0 + (c_ & 1);
            ws_s[c_][kk] = (k < 512) ? W_hh[(size_t)cg * 512 + k]
                                     : W_ih[(size_t)cg * 1536 + k];
        }
        __syncthreads();
        const int kb = ks * 64;
#pragma unroll 8
        for (int kk = 0; kk < 64; kk++)
            acc += ws_s[cl][kb + kk] * xin_s[bb][kb + kk];
        __syncthreads();
    }
    part[ks][cl][bb] = acc;
    __syncthreads();
    if (tid < 32) {
        int jl = tid >> 4, b_ = tid & 15;
        int j = j0 + jl;
        const float* g = gx + ((size_t)t * 16 + b_) * 2048;
        float gi = part[0][0 + jl][b_] + part[1][0 + jl][b_] + g[j];
        float gf = part[0][2 + jl][b_] + part[1][2 + jl][b_] + g[j + 512];
        float gg = part[0][4 + jl][b_] + part[1][4 + jl][b_] + g[j + 1024];
        float go = part[0][6 + jl][b_] + part[1][6 + jl][b_] + g[j + 1536];
        float cc = sigmf(gf) * cbuf[b_ * 512 + j] + sigmf(gi) * tanhf(gg);
        float hh = sigmf(go) * tanhf(cc);
        cbuf[b_ * 512 + j] = cc;
        h_out[b_ * 512 + j] = hh;
        hr[((size_t)t * 16 + b_) * 1536 + j] = hh;
    }
}

// ---------------------------------------------------------------------------
// Per-step: xi[b,q] = b_int[q] + sum_k h[b,k] * W_int[k*2573+q]
// Block: 16 q columns, all 16 b. Grid 161.
// ---------------------------------------------------------------------------
__global__ __launch_bounds__(256) void k_xi(
    const float* __restrict__ W_int, const float* __restrict__ b_int,
    const float* __restrict__ h, float* __restrict__ xi)
{
    __shared__ float h_s[16][516];
    const int tid = threadIdx.x;
    for (int i = tid; i < 8192; i += 256) h_s[i >> 9][i & 511] = h[i];
    __syncthreads();
    const int ql = tid & 15, bb = tid >> 4;
    const int q = blockIdx.x * 16 + ql;
    const int qc = (q < 2573) ? q : 2572;
    float acc = 0.f;
#pragma unroll 4
    for (int k = 0; k < 512; k++)
        acc += h_s[bb][k] * W_int[(size_t)k * 2573 + qc];
    if (q < 2573) xi[bb * 2573 + q] = acc + b_int[q];
}

// ---------------------------------------------------------------------------
// block reduce helper: each thread holds v[K]; result in outp[0..K)
// ---------------------------------------------------------------------------
template <int K>
__device__ __forceinline__ void blk_reduce(float* v, float (*s_red)[20],
                                           float* outp, int tid)
{
#pragma unroll
    for (int i = 0; i < K; i++) {
        float x = v[i];
        for (int o = 32; o > 0; o >>= 1) x += __shfl_down(x, o, 64);
        if ((tid & 63) == 0) s_red[tid >> 6][i] = x;
    }
    __syncthreads();
    if (tid < K) outp[tid] = s_red[0][tid] + s_red[1][tid] + s_red[2][tid] + s_red[3][tid];
    __syncthreads();
}

// ---------------------------------------------------------------------------
// Per-step memory machinery: one block per batch element.
// ---------------------------------------------------------------------------
__global__ __launch_bounds__(256) void k_mem(int t,
    const float* __restrict__ xi, float* __restrict__ M,
    float* __restrict__ u, float* __restrict__ p, float* __restrict__ L,
    float* __restrict__ wr, float* __restrict__ ww, float* __restrict__ r,
    float* __restrict__ hr)
{
    const int b = blockIdx.x;
    const int tid = threadIdx.x;
    const float* xb = xi + b * 2573;
    float* Mb = M + b * (5 * 512);

    __shared__ float s_rb[2], s_wb, s_fg[2], s_ga, s_gw, s_pi[2][3];
    __shared__ float s_wrold[2][5], s_u[5], s_a[5], s_ww[5];
    __shared__ float s_pold[5], s_Lnew[25];
    __shared__ float s_zw[5], s_z[2][5], s_fw[2][5], s_bw[2][5];
    __shared__ float s_red[4][20];
    __shared__ float s_dotA[11];    // [||M||^2 x5, wk.M x5, ||wk||^2]
    __shared__ float s_dotB[17];    // [||M'||^2 x5, rk0.M' x5, rk1.M' x5, ||rk0||^2, ||rk1||^2]
    __shared__ float s_wrnew[2][5];
    __shared__ float s_M[5][516];

    // Phase 0: scalars + small old state
    if (tid == 0) {
        s_wb = oneplusf(xb[1538]);
        s_ga = sigmf(xb[2565]);
        s_gw = sigmf(xb[2566]);
    }
    if (tid == 1 || tid == 2) {
        int rr = tid - 1;
        s_rb[rr] = oneplusf(xb[1024 + rr]);
        s_fg[rr] = sigmf(xb[2563 + rr]);
        float z0 = xb[2567 + rr * 3], z1 = xb[2568 + rr * 3], z2 = xb[2569 + rr * 3];
        float mx = fmaxf(z0, fmaxf(z1, z2));
        float e0 = expf(z0 - mx), e1 = expf(z1 - mx), e2 = expf(z2 - mx);
        float s = e0 + e1 + e2;
        s_pi[rr][0] = e0 / s; s_pi[rr][1] = e1 / s; s_pi[rr][2] = e2 / s;
    }
    if (tid >= 32 && tid < 42) { int i = tid - 32; s_wrold[i / 5][i % 5] = wr[b * 10 + i]; }
    if (tid >= 64 && tid < 69) { s_pold[tid - 64] = p[b * 5 + (tid - 64)]; }
    __syncthreads();

    // Phase 1: psi, usage update (uses OLD ww)
    if (tid < 5) {
        int n = tid;
        float psi = (1.f - s_fg[0] * s_wrold[0][n]) * (1.f - s_fg[1] * s_wrold[1][n]);
        float uo = u[b * 5 + n], wo = ww[b * 5 + n];
        float un = (uo + wo - uo * wo) * psi;
        s_u[n] = un;
        u[b * 5 + n] = un;
    }
    __syncthreads();

    // Phase 2a: allocation weighting (stable ascending argsort semantics)
    if (tid < 5) {
        int n = tid;
        float excl = 1.f;
#pragma unroll
        for (int m2 = 0; m2 < 5; m2++) {
            bool before = (s_u[m2] < s_u[n]) || (s_u[m2] == s_u[n] && m2 < n);
            if (before) excl *= s_u[m2];
        }
        s_a[n] = (1.f - s_u[n]) * excl;
    }
    // Phase 2b: dots vs OLD M
    float accA[11];
#pragma unroll
    for (int i = 0; i < 11; i++) accA[i] = 0.f;
    for (int w = tid; w < 512; w += 256) {
        float wkw = xb[1026 + w];
        accA[10] += wkw * wkw;
#pragma unroll
        for (int n = 0; n < 5; n++) {
            float m_ = Mb[n * 512 + w];
            accA[n] += m_ * m_;
            accA[5 + n] += wkw * m_;
        }
    }
    blk_reduce<11>(accA, s_red, s_dotA, tid);

    // Phase 2c: write content weight -> ww
    if (tid < 5) {
        float sim = s_dotA[5 + tid] / ((sqrtf(s_dotA[10]) + EPSC) * (sqrtf(s_dotA[tid]) + EPSC));
        s_zw[tid] = s_wb * sim;
    }
    __syncthreads();
    if (tid < 5) {
        float mx = s_zw[0];
#pragma unroll
        for (int m2 = 1; m2 < 5; m2++) mx = fmaxf(mx, s_zw[m2]);
        float sum = 0.f;
#pragma unroll
        for (int m2 = 0; m2 < 5; m2++) sum += expf(s_zw[m2] - mx);
        float cw = expf(s_zw[tid] - mx) / sum;
        float w_ = s_gw * (s_ga * s_a[tid] + (1.f - s_ga) * cw);
        s_ww[tid] = w_;
        ww[b * 5 + tid] = w_;
    }
    __syncthreads();

    // Phase 3: memory write + dots vs NEW M
    float accB[17];
#pragma unroll
    for (int i = 0; i < 17; i++) accB[i] = 0.f;
    for (int w = tid; w < 512; w += 256) {
        float ew = sigmf(xb[1539 + w]);
        float vw = xb[2051 + w];
        float rk0 = xb[w], rk1 = xb[512 + w];
        accB[15] += rk0 * rk0; accB[16] += rk1 * rk1;
#pragma unroll
        for (int n = 0; n < 5; n++) {
            float m_ = Mb[n * 512 + w];
            float mn_ = m_ * (1.f - s_ww[n] * ew) + s_ww[n] * vw;
            Mb[n * 512 + w] = mn_;
            s_M[n][w] = mn_;
            accB[n] += mn_ * mn_;
            accB[5 + n] += rk0 * mn_;
            accB[10 + n] += rk1 * mn_;
        }
    }
    blk_reduce<17>(accB, s_red, s_dotB, tid);

    // Phase 4a: link matrix
    if (tid < 25) {
        int i2 = tid / 5, j2 = tid % 5;
        float Ln = (i2 == j2) ? 0.f
                 : (1.f - s_ww[i2] - s_ww[j2]) * L[b * 25 + tid] + s_ww[i2] * s_pold[j2];
        s_Lnew[tid] = Ln;
        L[b * 25 + tid] = Ln;
    }
    __syncthreads();
    // Phase 4b: precedence + fw/bw + content-read logits
    if (tid < 5) {
        float wsum = s_ww[0] + s_ww[1] + s_ww[2] + s_ww[3] + s_ww[4];
        p[b * 5 + tid] = (1.f - wsum) * s_pold[tid] + s_ww[tid];
    }
    if (tid < 10) {
        int rr = tid / 5, ii = tid % 5;
        float fw = 0.f, bw = 0.f;
#pragma unroll
        for (int j2 = 0; j2 < 5; j2++) {
            fw += s_Lnew[ii * 5 + j2] * s_wrold[rr][j2];
            bw += s_Lnew[j2 * 5 + ii] * s_wrold[rr][j2];
        }
        s_fw[rr][ii] = fw; s_bw[rr][ii] = bw;
        float sim = s_dotB[5 + rr * 5 + ii] /
                    ((sqrtf(s_dotB[15 + rr]) + EPSC) * (sqrtf(s_dotB[ii]) + EPSC));
        s_z[rr][ii] = s_rb[rr] * sim;
    }
    __syncthreads();
    // Phase 4c: read weights
    if (tid < 10) {
        int rr = tid / 5, ii = tid % 5;
        float mx = s_z[rr][0];
#pragma unroll
        for (int m2 = 1; m2 < 5; m2++) mx = fmaxf(mx, s_z[rr][m2]);
        float sum = 0.f;
#pragma unroll
        for (int m2 = 0; m2 < 5; m2++) sum += expf(s_z[rr][m2] - mx);
        float cr = expf(s_z[rr][ii] - mx) / sum;
        float wn = s_pi[rr][0] * s_bw[rr][ii] + s_pi[rr][1] * cr + s_pi[rr][2] * s_fw[rr][ii];
        s_wrnew[rr][ii] = wn;
        wr[b * 10 + rr * 5 + ii] = wn;
    }
    __syncthreads();
    // Phase 5: read vectors
    for (int idx = tid; idx < 1024; idx += 256) {
        int rr = idx >> 9, w = idx & 511;
        float rv = 0.f;
#pragma unroll
        for (int n = 0; n < 5; n++) rv += s_wrnew[rr][n] * s_M[n][w];
        r[b * 1024 + idx] = rv;
        hr[((size_t)t * 16 + b) * 1536 + 512 + idx] = rv;
    }
}

// ---------------------------------------------------------------------------
// Epilogue: out[b,s,q] = b_out[q] + sum_k hr[s,b,k]*W_out[k,q]
// GEMM M=2048 (tok=s*16+b), N=512, K=1536.
// ---------------------------------------------------------------------------
__global__ __launch_bounds__(256) void k_out(
    const float* __restrict__ hr, const float* __restrict__ W_out,
    const float* __restrict__ b_out, float* __restrict__ out)
{
    __shared__ float As[16][65];
    __shared__ float Bs[16][65];
    const int tid = threadIdx.x;
    const int bm = blockIdx.x, bn = blockIdx.y;
    const int tm = tid >> 4, tn = tid & 15;
    float acc[4][4] = {};
    for (int k0 = 0; k0 < 1536; k0 += 16) {
#pragma unroll
        for (int i = 0; i < 4; i++) {
            int idx = tid + 256 * i;
            int m = idx >> 4, kk = idx & 15;
            As[kk][m] = hr[(size_t)(bm * 64 + m) * 1536 + k0 + kk];
        }
#pragma unroll
        for (int i = 0; i < 4; i++) {
            int idx = tid + 256 * i;
            int kk = idx >> 6, n = idx & 63;
            Bs[kk][n] = W_out[(size_t)(k0 + kk) * 512 + bn * 64 + n];
        }
        __syncthreads();
#pragma unroll
        for (int kk = 0; kk < 16; kk++) {
            float a[4], bv[4];
#pragma unroll
            for (int i = 0; i < 4; i++) a[i] = As[kk][tm * 4 + i];
#pragma unroll
            for (int j = 0; j < 4; j++) bv[j] = Bs[kk][tn * 4 + j];
#pragma unroll
            for (int i = 0; i < 4; i++)
#pragma unroll
                for (int j = 0; j < 4; j++) acc[i][j] += a[i] * bv[j];
        }
        __syncthreads();
    }
#pragma unroll
    for (int i = 0; i < 4; i++) {
        int tok = bm * 64 + tm * 4 + i;
        int b_ = tok & 15, s_ = tok >> 4;
#pragma unroll
        for (int j = 0; j < 4; j++) {
            int q = bn * 64 + tn * 4 + j;
            out[(size_t)((b_ << 7) + s_) * 512 + q] = acc[i][j] + b_out[q];
        }
    }
}

// copy final h, c into output tail
__global__ __launch_bounds__(256) void k_hc(
    const float* __restrict__ hfin, const float* __restrict__ cfin,
    float* __restrict__ out)
{
    int i = blockIdx.x * 256 + threadIdx.x;
    if (i < 8192) {
        out[1048576 + i] = hfin[i];
        out[1048576 + 8192 + i] = cfin[i];
    }
}

extern "C" void kernel_launch(void* const* d_in, const int* in_sizes, int n_in,
                              void* d_out, int out_size, void* d_ws, size_t ws_size,
                              hipStream_t stream)
{
    const int*   src    = (const int*)d_in[0];
    // d_in[1] = source_lengths (unused by reference)
    const float* emb    = (const float*)d_in[2];
    const float* W_ih   = (const float*)d_in[3];
    const float* W_hh   = (const float*)d_in[4];
    const float* b_lstm = (const float*)d_in[5];
    const float* W_int  = (const float*)d_in[6];
    const float* b_int  = (const float*)d_in[7];
    const float* W_out  = (const float*)d_in[8];
    const float* b_out  = (const float*)d_in[9];

    float* ws   = (float*)d_ws;
    float* out  = (float*)d_out;

    float* hbuf = ws + OFF_H;
    float* cbuf = ws + OFF_C;
    float* rbuf = ws + OFF_R;
    float* Mb   = ws + OFF_M;
    float* ub   = ws + OFF_U;
    float* pb   = ws + OFF_P;
    float* Lb   = ws + OFF_L;
    float* wrb  = ws + OFF_WR;
    float* wwb  = ws + OFF_WW;
    float* xib  = ws + OFF_XI;
    float* gx   = ws + OFF_GX;
    float* hrb  = ws + OFF_HR;

    // zero the recurrent state (deterministic across replays)
    hipMemsetAsync(ws, 0, STATE_END * sizeof(float), stream);

    // prologue: token-parallel x-part of gates (+ bias)
    k_embgx<<<dim3(32, 32), 256, 0, stream>>>(src, emb, W_ih, b_lstm, gx);

    for (int t = 0; t < 128; t++) {
        float* h_in  = hbuf + (t & 1) * 8192;
        float* h_out = hbuf + ((t + 1) & 1) * 8192;
        k_lstm<<<256, 256, 0, stream>>>(t, W_ih, W_hh, gx, h_in, rbuf, h_out, cbuf, hrb);
        k_xi<<<161, 256, 0, stream>>>(W_int, b_int, h_out, xib);
        k_mem<<<16, 256, 0, stream>>>(t, xib, Mb, ub, pb, Lb, wrb, wwb, rbuf, hrb);
    }

    // epilogue: token-parallel output projection
    k_out<<<dim3(32, 8), 256, 0, stream>>>(hrb, W_out, b_out, out);
    // final (h, c) — after 128 steps the final h lives in hbuf[0]
    k_hc<<<32, 256, 0, stream>>>(hbuf, cbuf, out);
}